// Round 8
// baseline (290.270 us; speedup 1.0000x reference)
//
#include <hip/hip_runtime.h>
#include <stdint.h>

// HashGrid encode, instant-ngp/tcnn defaults, Smoothstep interpolation.
// 16 levels, F=2, T=2^19, base_res=16, per_level_scale=2.0, 2D input.
// Levels 0..5 dense (res=16<<l, res^2 <= T), levels 6..15 hashed (4 MiB each).
//
// Round 8: level-major two-kernel scheme, rebalanced + coalesced transpose.
//  K1 (gather): work item = (level, 1024-pt chunk). Weighted schedule
//      (dense=1, hashed=2) splits the level-major item list into 8 equal
//      weighted shares, one per XCD (bid&7 -> XCD, round-robin dispatch).
//      Each hashed table lives in <=2 XCDs' L2 (round 7 proved 1-XCD binding
//      drops FETCH 494->76 MB); critical XCD now carries ~1.25 hashed levels
//      instead of 2. 4 pts/thread -> 16 gathers in flight. Scratch written
//      level-major [16][N][2] with contiguous 32B NT stores (bypass L2, keep
//      tables resident).
//  K2 (transpose): 256 pts/block staged via LDS (rows padded to 33 floats,
//      conflict-free), stores fully coalesced (4KB/wave). Round 7's transpose
//      was ~130us because each 16B lane-store hit a distinct 128B line.
// Fallback to round-6 single kernel if ws_size < 64 MB.

#define HG_LEVELS 16
#define HG_T (1u << 19)
#define HG_PRIME1 2654435761u

typedef float vfloat2 __attribute__((ext_vector_type(2)));
typedef float vfloat4 __attribute__((ext_vector_type(4)));

// Weighted schedule: level l occupies CH=512 chunks of weight w_l
// (w=1 dense l<6, w=2 hashed l>=6). Total weight TW = 6*512 + 10*1024 = 13312.
// XCD x owns weighted range [x*1664, (x+1)*1664). g = l*512 + c (level-major).
__device__ __forceinline__ int schedule_glo(int x)
{
    const int target = 1664 * x;   // TW/8 * x
#pragma unroll
    for (int l = 0; l < 16; ++l) {
        const int w = (l < 6) ? 1 : 2;
        const int base = (l < 6) ? (l * 512) : (3072 + (l - 6) * 1024);
        const int next = base + 512 * w;
        if (target < next) {
            int c = (target > base) ? (target - base + (w - 1)) / w : 0;
            return l * 512 + c;    // c may be 512 == start of level l+1: fine
        }
    }
    return 8192;
}

// ---------------- K1: level-major gather, 4 pts/thread ----------------
__global__ __launch_bounds__(256) void hg_gather_kernel(
    const float* __restrict__ x,        // [N][2] in [-1,1]
    const float* __restrict__ table,    // [16][T][2]
    float* __restrict__ scratch,        // [16][N][2]
    int npts)
{
    const int xcd = blockIdx.x & 7;
    const int j = blockIdx.x >> 3;
    const int glo = schedule_glo(xcd);
    const int ghi = schedule_glo(xcd + 1);
    const int g = glo + j;
    if (g >= ghi) return;               // no syncthreads in this kernel

    const int level = g >> 9;
    const int chunk = g & 511;

    int p0 = chunk * 1024 + 4 * (int)threadIdx.x;
    if (p0 + 3 >= npts) p0 = npts - 4;  // benign duplicate on tail

    vfloat4 xa = __builtin_nontemporal_load((const vfloat4*)(x + 2 * (size_t)p0));
    vfloat4 xb = __builtin_nontemporal_load((const vfloat4*)(x + 2 * (size_t)p0 + 4));
    float px[4] = { xa.x, xa.z, xb.x, xb.z };
    float py[4] = { xa.y, xa.w, xb.y, xb.w };

    const int res = 16 << level;                 // = ceil(scale)+1, exact
    const float scale = (float)res - 1.0f;       // exactly representable
    const bool dense = (level <= 5);
    const uint32_t dmask = (uint32_t)res * (uint32_t)res - 1u;  // pow2 if dense

    uint32_t idx[4][4];
    float ww[4][4];
#pragma unroll
    for (int k = 0; k < 4; ++k) {
        float u0 = px[k] * 0.5f + 0.5f;
        float u1 = py[k] * 0.5f + 0.5f;
        float p0f = u0 * scale + 0.5f;
        float p1f = u1 * scale + 0.5f;
        float g0 = floorf(p0f), g1 = floorf(p1f);
        float fr0 = p0f - g0, fr1 = p1f - g1;
        uint32_t c0 = (uint32_t)(int)g0;         // pos >= 0.5 so >= 0
        uint32_t c1 = (uint32_t)(int)g1;
        float w0 = fr0 * fr0 * (3.0f - 2.0f * fr0);  // smoothstep
        float w1 = fr1 * fr1 * (3.0f - 2.0f * fr1);

        if (dense) {
            uint32_t b0 = c1 * (uint32_t)res;
            uint32_t b1 = (c1 + 1u) * (uint32_t)res;
            idx[k][0] = (c0 + b0) & dmask;
            idx[k][1] = (c0 + 1u + b0) & dmask;
            idx[k][2] = (c0 + b1) & dmask;
            idx[k][3] = (c0 + 1u + b1) & dmask;
        } else {
            uint32_t h0 = c1 * HG_PRIME1;
            uint32_t h1 = (c1 + 1u) * HG_PRIME1;
            idx[k][0] = (c0 ^ h0) & (HG_T - 1u);
            idx[k][1] = ((c0 + 1u) ^ h0) & (HG_T - 1u);
            idx[k][2] = (c0 ^ h1) & (HG_T - 1u);
            idx[k][3] = ((c0 + 1u) ^ h1) & (HG_T - 1u);
        }
        ww[k][0] = (1.0f - w0) * (1.0f - w1);
        ww[k][1] = w0 * (1.0f - w1);
        ww[k][2] = (1.0f - w0) * w1;
        ww[k][3] = w0 * w1;
    }

    const float2* tl = (const float2*)(table + (size_t)level * (size_t)HG_T * 2u);
    float2 ft[4][4];
#pragma unroll
    for (int k = 0; k < 4; ++k)
#pragma unroll
        for (int c = 0; c < 4; ++c)
            ft[k][c] = tl[idx[k][c]];            // 16 independent gathers

    float sx[4], sy[4];
#pragma unroll
    for (int k = 0; k < 4; ++k) {
        float ax = 0.f, ay = 0.f;
#pragma unroll
        for (int c = 0; c < 4; ++c) {
            ax += ww[k][c] * ft[k][c].x;
            ay += ww[k][c] * ft[k][c].y;
        }
        sx[k] = ax; sy[k] = ay;
    }

    // scratch[level][p0..p0+3][2]: 32B contiguous per thread, NT (keep L2 for tables)
    float* sp = scratch + ((size_t)level * (size_t)npts + (size_t)p0) * 2u;
    vfloat4 v0 = { sx[0], sy[0], sx[1], sy[1] };
    vfloat4 v1 = { sx[2], sy[2], sx[3], sy[3] };
    __builtin_nontemporal_store(v0, (vfloat4*)sp);
    __builtin_nontemporal_store(v1, (vfloat4*)(sp + 4));
}

// ---------------- K2: LDS transpose scratch -> out ----------------
__global__ __launch_bounds__(256) void hg_transpose_kernel(
    const float* __restrict__ scratch,  // [16][N][2]
    float* __restrict__ out,            // [N][32]
    int npts)
{
    __shared__ float lds[256 * 33];     // 33-float rows: conflict-free both phases
    const int t = (int)threadIdx.x;
    const int pbase = blockIdx.x * 256;

    // load: per level, 256 consecutive points' float2 -> coalesced 2KB
#pragma unroll
    for (int l = 0; l < 16; ++l) {
        int p = pbase + t;
        if (p >= npts) p = npts - 1;
        vfloat2 v = *(const vfloat2*)(scratch + ((size_t)l * (size_t)npts + (size_t)p) * 2u);
        lds[t * 33 + 2 * l + 0] = v.x;
        lds[t * 33 + 2 * l + 1] = v.y;
    }
    __syncthreads();

    // store: block's 256 rows = 8192 floats = 2048 float4, fully coalesced
    float* ob = out + (size_t)pbase * 32u;
#pragma unroll
    for (int jj = 0; jj < 8; ++jj) {
        int f = jj * 256 + t;           // float4 index within block
        int pl = f >> 3;                // local point
        int k = f & 7;                  // float4 piece within row
        vfloat4 v = { lds[pl * 33 + 4 * k + 0], lds[pl * 33 + 4 * k + 1],
                      lds[pl * 33 + 4 * k + 2], lds[pl * 33 + 4 * k + 3] };
        *(vfloat4*)(ob + 4 * (size_t)f) = v;
    }
}

// ---------------- Fallback (round-6 style, known-good 184us) ----------------
__global__ __launch_bounds__(256) void hg_fallback_kernel(
    const float4* __restrict__ x, const float* __restrict__ table,
    float* __restrict__ out, int npairs)
{
    int t = blockIdx.x * blockDim.x + threadIdx.x;
    if (t >= npairs) t = npairs - 1;
    float4 xp = x[t];
    float a0 = xp.x * 0.5f + 0.5f, a1 = xp.y * 0.5f + 0.5f;
    float b0 = xp.z * 0.5f + 0.5f, b1 = xp.w * 0.5f + 0.5f;
    float accA[32], accB[32];
#pragma unroll
    for (int l = 0; l < HG_LEVELS; ++l) {
        const int res = 16 << l;
        const float scale = (float)res - 1.0f;
        float pA0 = a0 * scale + 0.5f, pA1 = a1 * scale + 0.5f;
        float pB0 = b0 * scale + 0.5f, pB1 = b1 * scale + 0.5f;
        float gA0 = floorf(pA0), gA1 = floorf(pA1), gB0 = floorf(pB0), gB1 = floorf(pB1);
        float fA0 = pA0 - gA0, fA1 = pA1 - gA1, fB0 = pB0 - gB0, fB1 = pB1 - gB1;
        uint32_t cA0 = (uint32_t)(int)gA0, cA1 = (uint32_t)(int)gA1;
        uint32_t cB0 = (uint32_t)(int)gB0, cB1 = (uint32_t)(int)gB1;
        float wA0 = fA0 * fA0 * (3.0f - 2.0f * fA0), wA1 = fA1 * fA1 * (3.0f - 2.0f * fA1);
        float wB0 = fB0 * fB0 * (3.0f - 2.0f * fB0), wB1 = fB1 * fB1 * (3.0f - 2.0f * fB1);
        uint32_t iA[4], iB[4];
        if (l <= 5) {
            uint32_t mask = (uint32_t)res * (uint32_t)res - 1u;
            uint32_t bA0 = cA1 * (uint32_t)res, bA1 = (cA1 + 1u) * (uint32_t)res;
            uint32_t bB0 = cB1 * (uint32_t)res, bB1 = (cB1 + 1u) * (uint32_t)res;
            iA[0]=(cA0+bA0)&mask; iA[1]=(cA0+1u+bA0)&mask; iA[2]=(cA0+bA1)&mask; iA[3]=(cA0+1u+bA1)&mask;
            iB[0]=(cB0+bB0)&mask; iB[1]=(cB0+1u+bB0)&mask; iB[2]=(cB0+bB1)&mask; iB[3]=(cB0+1u+bB1)&mask;
        } else {
            uint32_t hA0 = cA1*HG_PRIME1, hA1 = (cA1+1u)*HG_PRIME1;
            uint32_t hB0 = cB1*HG_PRIME1, hB1 = (cB1+1u)*HG_PRIME1;
            iA[0]=(cA0^hA0)&(HG_T-1u); iA[1]=((cA0+1u)^hA0)&(HG_T-1u);
            iA[2]=(cA0^hA1)&(HG_T-1u); iA[3]=((cA0+1u)^hA1)&(HG_T-1u);
            iB[0]=(cB0^hB0)&(HG_T-1u); iB[1]=((cB0+1u)^hB0)&(HG_T-1u);
            iB[2]=(cB0^hB1)&(HG_T-1u); iB[3]=((cB0+1u)^hB1)&(HG_T-1u);
        }
        const float2* tl = (const float2*)(table + (size_t)l * (size_t)HG_T * 2u);
        float2 fa[4], fb[4];
#pragma unroll
        for (int c = 0; c < 4; ++c) fa[c] = tl[iA[c]];
#pragma unroll
        for (int c = 0; c < 4; ++c) fb[c] = tl[iB[c]];
        float wwA[4] = {(1.f-wA0)*(1.f-wA1), wA0*(1.f-wA1), (1.f-wA0)*wA1, wA0*wA1};
        float wwB[4] = {(1.f-wB0)*(1.f-wB1), wB0*(1.f-wB1), (1.f-wB0)*wB1, wB0*wB1};
        float sAx=0.f,sAy=0.f,sBx=0.f,sBy=0.f;
#pragma unroll
        for (int c = 0; c < 4; ++c) {
            sAx += wwA[c]*fa[c].x; sAy += wwA[c]*fa[c].y;
            sBx += wwB[c]*fb[c].x; sBy += wwB[c]*fb[c].y;
        }
        accA[2*l]=sAx; accA[2*l+1]=sAy; accB[2*l]=sBx; accB[2*l+1]=sBy;
        if (l >= 5 && l < HG_LEVELS - 1) __syncthreads();
    }
    float4* oA = (float4*)(out + (size_t)(2*t+0)*32u);
    float4* oB = (float4*)(out + (size_t)(2*t+1)*32u);
#pragma unroll
    for (int j = 0; j < 8; ++j) oA[j] = make_float4(accA[4*j],accA[4*j+1],accA[4*j+2],accA[4*j+3]);
#pragma unroll
    for (int j = 0; j < 8; ++j) oB[j] = make_float4(accB[4*j],accB[4*j+1],accB[4*j+2],accB[4*j+3]);
}

extern "C" void kernel_launch(void* const* d_in, const int* in_sizes, int n_in,
                              void* d_out, int out_size, void* d_ws, size_t ws_size,
                              hipStream_t stream) {
    const float* x = (const float*)d_in[0];
    const float* table = (const float*)d_in[1];
    float* out = (float*)d_out;

    int npts = in_sizes[0] / 2;                       // 524288
    size_t need = (size_t)HG_LEVELS * (size_t)npts * 2u * sizeof(float);  // 64 MB

    if (ws_size >= need && d_ws != nullptr && (npts % 1024) == 0) {
        float* scratch = (float*)d_ws;
        // grid: 8 XCD slots x max blocks/XCD (XCD0's all-dense share = 1664)
        int grid1 = 8 * 1664;
        hg_gather_kernel<<<grid1, 256, 0, stream>>>(x, table, scratch, npts);
        int grid2 = (npts + 255) / 256;               // 2048
        hg_transpose_kernel<<<grid2, 256, 0, stream>>>(scratch, out, npts);
    } else {
        int npairs = npts / 2;
        int grid = (npairs + 255) / 256;
        hg_fallback_kernel<<<grid, 256, 0, stream>>>((const float4*)x, table, out, npairs);
    }
}